// Round 3
// baseline (93.665 us; speedup 1.0000x reference)
//
#include <hip/hip_runtime.h>
#include <stdint.h>

// Problem constants (reference: B,H,E,IN,OUT = 4096,1,8,256,256)
#define B_N   4096
#define E_N   8
#define IN_N  256
#define OUT_N 256
#define NMASK 256   // 2^E distinct gate patterns

// ---------------------------------------------------------------------------
// Kernel 1: build the per-mask binarized-weight bit table.
//   wbits[mask][o][j] (j=0..3), bit i2 = ( s(mask, i=64j+i2, o) < 0 )
// where s = left-fold sum over set experts in ASCENDING e order — bit-exact
// vs the reference fma chain acc=fma(gate_e, W_e, acc) (gate in {0.0,1.0}:
// fma(1,w,a)=a+w with single rounding, fma(0,w,a)=a exactly).
//
// Layout: grid (OUT/4, 4j) = (64,4) blocks x 256 thr. Thread = (lane=i2,
// wave=o'). Each W float is read EXACTLY ONCE across the whole grid (2 MB).
// Subset sums via highest-set-bit DP: appending the highest set bit to the
// left-fold of the lower bits reproduces the ascending left-fold exactly.
// The 64 lanes of a wave are the 64 i2 bits of one output word -> __ballot
// forms the word directly; lane 0 stores it.
// ---------------------------------------------------------------------------
__global__ __launch_bounds__(256) void build_wbits(const float* __restrict__ W,
                                                   uint64_t* __restrict__ wbits) {
    const int lane = threadIdx.x & 63;        // i2
    const int wv   = threadIdx.x >> 6;        // o sub-index (4 o's per block)
    const int o    = blockIdx.x * 4 + wv;
    const int j    = blockIdx.y;              // which 64-wide i word
    const int i    = j * 64 + lane;

    // load this (i,o)'s 8 expert weights: W[e][i][o]
    float w[E_N];
    #pragma unroll
    for (int e = 0; e < E_N; ++e)
        w[e] = W[((size_t)e * IN_N + i) * OUT_N + o];

    // left-fold sums of all low-nibble subsets (experts 0..3), ascending order
    float slo[16];
    slo[0] = 0.0f;
    #pragma unroll
    for (int m = 1; m < 16; ++m) {
        const int hb = 31 - __builtin_clz(m);       // constant after unroll
        slo[m] = slo[m ^ (1 << hb)] + w[hb];
    }

    #pragma unroll 1
    for (int lo = 0; lo < 16; ++lo) {
        // append high-nibble subsets (experts 4..7), ascending, via same DP
        float t[16];
        t[0] = slo[lo];
        #pragma unroll
        for (int h = 1; h < 16; ++h) {
            const int hb = 31 - __builtin_clz(h);
            t[h] = t[h ^ (1 << hb)] + w[4 + hb];
        }
        #pragma unroll
        for (int h = 0; h < 16; ++h) {
            const int mask = h * 16 + lo;
            const unsigned long long bits = __ballot(t[h] < 0.0f);
            if (lane == 0)
                wbits[((size_t)mask * OUT_N + o) * 4 + j] = bits;
        }
    }
}

// ---------------------------------------------------------------------------
// Kernel 2 (fused): per-sample gate + x sign bits + XNOR-popcount GEMV.
// Block = one sample b, 256 threads (thread = output o; also = input i for
// staging).  gate_e = (x[b]·proj_w[e] + proj_b[e]) > 0   (sigmoid>0.5 <=> z>0)
//   y[b,o] = scale[o] * (IN - nzero - 2*popc((xbits ^ wbits[mask]) & ~zbits))
// zbits marks x==0 exactly (sign(0)=0). mask==0 => w==0 => sign(w)=0 => y=0.
// ---------------------------------------------------------------------------
__global__ __launch_bounds__(256) void gate_gemv(const float* __restrict__ x,
                                                 const float* __restrict__ pw,
                                                 const float* __restrict__ pb,
                                                 const float* __restrict__ scale,
                                                 const uint64_t* __restrict__ wbits,
                                                 float* __restrict__ out) {
    const int b    = blockIdx.x;
    const int t    = threadIdx.x;
    const int wave = t >> 6;
    const int lane = t & 63;

    __shared__ float              partial[4][E_N];
    __shared__ unsigned long long xw[4], zw[4];
    __shared__ uint32_t           mask_s;

    const float xi = x[(size_t)b * IN_N + t];

    // sign / zero bitplanes of x[b] (64 lanes -> one word per wave)
    const unsigned long long sb = __ballot(xi < 0.0f);
    const unsigned long long zb = __ballot(xi == 0.0f);
    if (lane == 0) { xw[wave] = sb; zw[wave] = zb; }

    // gate dot-products: 8 wave-tree reductions, combined across 4 waves
    #pragma unroll
    for (int e = 0; e < E_N; ++e) {
        float v = xi * pw[e * IN_N + t];
        v += __shfl_down(v, 32); v += __shfl_down(v, 16); v += __shfl_down(v, 8);
        v += __shfl_down(v, 4);  v += __shfl_down(v, 2);  v += __shfl_down(v, 1);
        if (lane == 0) partial[wave][e] = v;
    }
    __syncthreads();

    if (t == 0) {
        uint32_t m = 0;
        #pragma unroll
        for (int e = 0; e < E_N; ++e) {
            const float z = ((partial[0][e] + partial[1][e]) +
                             (partial[2][e] + partial[3][e])) + pb[e];
            if (z > 0.0f) m |= (1u << e);
        }
        mask_s = m;
    }
    __syncthreads();

    const uint32_t m = mask_s;
    float y = 0.0f;
    if (m != 0u) {
        const uint64_t* wp = wbits + ((size_t)m * OUT_N + t) * 4;
        const ulonglong2 wa = *reinterpret_cast<const ulonglong2*>(wp);
        const ulonglong2 wb2 = *reinterpret_cast<const ulonglong2*>(wp + 2);
        const uint64_t x0 = xw[0], x1 = xw[1], x2 = xw[2], x3 = xw[3];
        const uint64_t z0 = zw[0], z1 = zw[1], z2 = zw[2], z3 = zw[3];
        const int nz = __popcll(z0) + __popcll(z1) + __popcll(z2) + __popcll(z3);
        const int d  = __popcll((x0 ^ wa.x) & ~z0)
                     + __popcll((x1 ^ wa.y) & ~z1)
                     + __popcll((x2 ^ wb2.x) & ~z2)
                     + __popcll((x3 ^ wb2.y) & ~z3);
        y = (float)(IN_N - nz - 2 * d) * scale[t];
    }
    out[(size_t)b * OUT_N + t] = y;
}

// ---------------------------------------------------------------------------
extern "C" void kernel_launch(void* const* d_in, const int* in_sizes, int n_in,
                              void* d_out, int out_size, void* d_ws, size_t ws_size,
                              hipStream_t stream) {
    const float* x     = (const float*)d_in[0];   // [B,1,IN]
    const float* W     = (const float*)d_in[1];   // [1,E,IN,OUT]
    const float* pw    = (const float*)d_in[2];   // [E,IN]
    const float* pb    = (const float*)d_in[3];   // [E]
    const float* scale = (const float*)d_in[4];   // [1,1,OUT]
    float*       out   = (float*)d_out;           // [B,1,OUT]

    uint64_t* wbits = (uint64_t*)d_ws;            // NMASK*OUT_N*4 u64 = 2 MiB

    hipLaunchKernelGGL(build_wbits, dim3(OUT_N / 4, 4), dim3(256), 0, stream,
                       W, wbits);
    hipLaunchKernelGGL(gate_gemv, dim3(B_N), dim3(256), 0, stream,
                       x, pw, pb, scale, wbits, out);
}

// Round 4
// 82.231 us; speedup vs baseline: 1.1390x; 1.1390x over previous
//
#include <hip/hip_runtime.h>
#include <stdint.h>

// Problem constants (reference: B,H,E,IN,OUT = 4096,1,8,256,256)
#define B_N   4096
#define E_N   8
#define IN_N  256
#define OUT_N 256
#define NMASK 256   // 2^E distinct gate patterns

// ---------------------------------------------------------------------------
// Kernel 1: build the per-mask binarized-weight bit table.
//   wbits[mask][o][j] (j=0..3), bit i2 = ( s(mask, i=64j+i2, o) < 0 )
// where s = left-fold sum over set experts in ASCENDING e order — bit-exact
// vs the reference chain acc += gate_e * W_e (gate in {0.0,1.0}: adding
// exact 0.0 is an identity).
//
// Layout: grid (OUT/4, 4j) = (64,4) blocks x 256 thr. Thread = (lane=i2,
// wave=o'). Each W float is read EXACTLY ONCE across the whole grid (2 MB).
// Subset sums via highest-set-bit DP: appending the highest set bit to the
// left-fold of the lower bits reproduces the ascending left-fold exactly.
// The 64 lanes of a wave are the 64 i2 bits of one output word -> __ballot
// forms the word directly; lane 0 stores it.
// ---------------------------------------------------------------------------
__global__ __launch_bounds__(256) void build_wbits(const float* __restrict__ W,
                                                   uint64_t* __restrict__ wbits) {
    const int lane = threadIdx.x & 63;        // i2
    const int wv   = threadIdx.x >> 6;        // o sub-index (4 o's per block)
    const int o    = blockIdx.x * 4 + wv;
    const int j    = blockIdx.y;              // which 64-wide i word
    const int i    = j * 64 + lane;

    // load this (i,o)'s 8 expert weights: W[e][i][o]
    float w[E_N];
    #pragma unroll
    for (int e = 0; e < E_N; ++e)
        w[e] = W[((size_t)e * IN_N + i) * OUT_N + o];

    // left-fold sums of all low-nibble subsets (experts 0..3), ascending order
    float slo[16];
    slo[0] = 0.0f;
    #pragma unroll
    for (int m = 1; m < 16; ++m) {
        const int hb = 31 - __builtin_clz(m);       // constant after unroll
        slo[m] = slo[m ^ (1 << hb)] + w[hb];
    }

    #pragma unroll 1
    for (int lo = 0; lo < 16; ++lo) {
        // append high-nibble subsets (experts 4..7), ascending, via same DP
        float t[16];
        t[0] = slo[lo];
        #pragma unroll
        for (int h = 1; h < 16; ++h) {
            const int hb = 31 - __builtin_clz(h);
            t[h] = t[h ^ (1 << hb)] + w[4 + hb];
        }
        #pragma unroll
        for (int h = 0; h < 16; ++h) {
            const int mask = h * 16 + lo;
            const unsigned long long bits = __ballot(t[h] < 0.0f);
            if (lane == 0)
                wbits[((size_t)mask * OUT_N + o) * 4 + j] = bits;
        }
    }
}

// ---------------------------------------------------------------------------
// Kernel 2 (fused, wave-per-sample): gate + x sign bits + XNOR-popcount GEMV.
// Grid: B/4 blocks x 256 thr = 4 waves; wave w owns sample b = blk*4+w.
// No LDS, no __syncthreads, no serial section:
//  - lane l loads x[b][64j+l], j=0..3  -> __ballot gives sign/zero word j
//  - gate z_e via butterfly __shfl_xor all-reduce (fp add is commutative, so
//    every lane computes the identical tree -> identical z_e -> uniform mask)
//  - lane l emits outputs o = 64q+l, q=0..3 via coalesced wbits/scale/out
//   y[b,o] = scale[o] * (IN - nzero - 2*popc((xbits ^ wbits[mask]) & ~zbits))
// zbits marks x==0 exactly (sign(0)=0). mask==0 => w==0 => sign(w)=0 => y=0.
// ---------------------------------------------------------------------------
__global__ __launch_bounds__(256) void gate_gemv(const float* __restrict__ x,
                                                 const float* __restrict__ pw,
                                                 const float* __restrict__ pb,
                                                 const float* __restrict__ scale,
                                                 const uint64_t* __restrict__ wbits,
                                                 float* __restrict__ out) {
    const int lane = threadIdx.x & 63;
    const int wv   = threadIdx.x >> 6;
    const int b    = blockIdx.x * 4 + wv;

    const float* xb = x + (size_t)b * IN_N;
    float xs[4];
    #pragma unroll
    for (int j = 0; j < 4; ++j) xs[j] = xb[j * 64 + lane];

    // sign / zero bitplanes: word j covers i = 64j .. 64j+63 (bit = lane)
    uint64_t xw[4], zw[4];
    #pragma unroll
    for (int j = 0; j < 4; ++j) {
        xw[j] = __ballot(xs[j] <  0.0f);
        zw[j] = __ballot(xs[j] == 0.0f);
    }

    // gates: z_e = x[b]·pw[e] + pb[e];  sigmoid(z)>0.5  <=>  z>0
    uint32_t mask = 0u;
    #pragma unroll
    for (int e = 0; e < E_N; ++e) {
        const float* pwe = pw + e * IN_N;
        float v = xs[0] * pwe[lane];
        v += xs[1] * pwe[ 64 + lane];
        v += xs[2] * pwe[128 + lane];
        v += xs[3] * pwe[192 + lane];
        v += __shfl_xor(v, 1);  v += __shfl_xor(v, 2);  v += __shfl_xor(v, 4);
        v += __shfl_xor(v, 8);  v += __shfl_xor(v, 16); v += __shfl_xor(v, 32);
        if (v + pb[e] > 0.0f) mask |= (1u << e);     // uniform across wave
    }

    float* ob = out + (size_t)b * OUT_N;
    if (mask != 0u) {                                 // wave-uniform branch
        const uint64_t* wp = wbits + (size_t)mask * (OUT_N * 4);
        const int nz = __popcll(zw[0]) + __popcll(zw[1]) +
                       __popcll(zw[2]) + __popcll(zw[3]);
        const int base = IN_N - nz;
        #pragma unroll
        for (int q = 0; q < 4; ++q) {
            const int o = q * 64 + lane;
            const uint64_t* w4 = wp + (size_t)o * 4;
            const ulonglong2 a  = *reinterpret_cast<const ulonglong2*>(w4);
            const ulonglong2 c  = *reinterpret_cast<const ulonglong2*>(w4 + 2);
            const int d = __popcll((xw[0] ^ a.x) & ~zw[0])
                        + __popcll((xw[1] ^ a.y) & ~zw[1])
                        + __popcll((xw[2] ^ c.x) & ~zw[2])
                        + __popcll((xw[3] ^ c.y) & ~zw[3]);
            ob[o] = (float)(base - 2 * d) * scale[o];
        }
    } else {
        #pragma unroll
        for (int q = 0; q < 4; ++q) ob[q * 64 + lane] = 0.0f;
    }
}

// ---------------------------------------------------------------------------
extern "C" void kernel_launch(void* const* d_in, const int* in_sizes, int n_in,
                              void* d_out, int out_size, void* d_ws, size_t ws_size,
                              hipStream_t stream) {
    const float* x     = (const float*)d_in[0];   // [B,1,IN]
    const float* W     = (const float*)d_in[1];   // [1,E,IN,OUT]
    const float* pw    = (const float*)d_in[2];   // [E,IN]
    const float* pb    = (const float*)d_in[3];   // [E]
    const float* scale = (const float*)d_in[4];   // [1,1,OUT]
    float*       out   = (float*)d_out;           // [B,1,OUT]

    uint64_t* wbits = (uint64_t*)d_ws;            // NMASK*OUT_N*4 u64 = 2 MiB

    hipLaunchKernelGGL(build_wbits, dim3(OUT_N / 4, 4), dim3(256), 0, stream,
                       W, wbits);
    hipLaunchKernelGGL(gate_gemv, dim3(B_N / 4), dim3(256), 0, stream,
                       x, pw, pb, scale, wbits, out);
}

// Round 8
// 81.690 us; speedup vs baseline: 1.1466x; 1.0066x over previous
//
#include <hip/hip_runtime.h>
#include <stdint.h>

// Problem constants (reference: B,H,E,IN,OUT = 4096,1,8,256,256)
#define B_N   4096
#define E_N   8
#define IN_N  256
#define OUT_N 256
#define NMASK 256   // 2^E distinct gate patterns

// ws layout: [0, 2MB) wbits u64[NMASK*OUT*4]; [2MB, +256KB) xz u64[B*8];
//            then masks u32[B]
#define WBITS_U64   (NMASK * OUT_N * 4)
#define XZ_OFF_U64  WBITS_U64

// ---------------------------------------------------------------------------
// Kernel A ("prep"): two independent block families in one launch.
//   blocks [0,256):   build wbits[mask][o][j] — bit i2 = sign of the ascending
//                     left-fold subset sum (bit-exact vs reference; identical
//                     code to the round-3/4 passing version).
//   blocks [256,1280): per-sample gate + x bitplanes (wave-per-sample,
//                     butterfly shfl_xor all-reduce — identical numerics to
//                     the round-4 passing version). Writes xw[4],zw[4],mask.
// No dependency between families -> no sync needed; shfl-heavy gate work
// overlaps VALU-heavy build work across CUs.
// ---------------------------------------------------------------------------
__global__ __launch_bounds__(256) void prep(const float* __restrict__ W,
                                            const float* __restrict__ x,
                                            const float* __restrict__ pw,
                                            const float* __restrict__ pb,
                                            uint64_t* __restrict__ wbits,
                                            uint64_t* __restrict__ xz,
                                            uint32_t* __restrict__ masks) {
    const int lane = threadIdx.x & 63;
    const int wv   = threadIdx.x >> 6;

    if (blockIdx.x < 256) {
        // ---------------- build family ----------------
        const int ox = blockIdx.x & 63;       // o-group
        const int j  = blockIdx.x >> 6;       // 64-wide i word
        const int o  = ox * 4 + wv;
        const int i  = j * 64 + lane;

        float w[E_N];
        #pragma unroll
        for (int e = 0; e < E_N; ++e)
            w[e] = W[((size_t)e * IN_N + i) * OUT_N + o];

        float slo[16];
        slo[0] = 0.0f;
        #pragma unroll
        for (int m = 1; m < 16; ++m) {
            const int hb = 31 - __builtin_clz(m);
            slo[m] = slo[m ^ (1 << hb)] + w[hb];
        }

        #pragma unroll 1
        for (int lo = 0; lo < 16; ++lo) {
            float t[16];
            t[0] = slo[lo];
            #pragma unroll
            for (int h = 1; h < 16; ++h) {
                const int hb = 31 - __builtin_clz(h);
                t[h] = t[h ^ (1 << hb)] + w[4 + hb];
            }
            #pragma unroll
            for (int h = 0; h < 16; ++h) {
                const int mask = h * 16 + lo;
                const unsigned long long bits = __ballot(t[h] < 0.0f);
                if (lane == 0)
                    wbits[((size_t)mask * OUT_N + o) * 4 + j] = bits;
            }
        }
    } else {
        // ---------------- gate family (wave-per-sample) ----------------
        const int b = (blockIdx.x - 256) * 4 + wv;

        const float* xb = x + (size_t)b * IN_N;
        float xs[4];
        #pragma unroll
        for (int j = 0; j < 4; ++j) xs[j] = xb[j * 64 + lane];

        uint64_t xw[4], zw[4];
        #pragma unroll
        for (int j = 0; j < 4; ++j) {
            xw[j] = __ballot(xs[j] <  0.0f);
            zw[j] = __ballot(xs[j] == 0.0f);
        }

        uint32_t mask = 0u;
        #pragma unroll
        for (int e = 0; e < E_N; ++e) {
            const float* pwe = pw + e * IN_N;
            float v = xs[0] * pwe[lane];
            v += xs[1] * pwe[ 64 + lane];
            v += xs[2] * pwe[128 + lane];
            v += xs[3] * pwe[192 + lane];
            v += __shfl_xor(v, 1);  v += __shfl_xor(v, 2);  v += __shfl_xor(v, 4);
            v += __shfl_xor(v, 8);  v += __shfl_xor(v, 16); v += __shfl_xor(v, 32);
            if (v + pb[e] > 0.0f) mask |= (1u << e);     // uniform across wave
        }

        if (lane == 0) {
            uint64_t* s = xz + (size_t)b * 8;
            s[0] = xw[0]; s[1] = xw[1]; s[2] = xw[2]; s[3] = xw[3];
            s[4] = zw[0]; s[5] = zw[1]; s[6] = zw[2]; s[7] = zw[3];
            masks[b] = mask;
        }
    }
}

// ---------------------------------------------------------------------------
// Kernel B: pure XNOR-popcount GEMV. Wave-per-sample, no shfl, no LDS.
//   y[b,o] = scale[o] * (IN - nzero - 2*popc((xbits ^ wbits[mask]) & ~zbits))
// mask==0 => synthesized w==0 => sign(w)=0 => y=0 exactly.
// ---------------------------------------------------------------------------
__global__ __launch_bounds__(256) void popc_gemv(const uint64_t* __restrict__ wbits,
                                                 const uint64_t* __restrict__ xz,
                                                 const uint32_t* __restrict__ masks,
                                                 const float* __restrict__ scale,
                                                 float* __restrict__ out) {
    const int lane = threadIdx.x & 63;
    const int wv   = threadIdx.x >> 6;
    const int b    = blockIdx.x * 4 + wv;

    const uint32_t m = masks[b];              // wave-uniform
    float* ob = out + (size_t)b * OUT_N;

    if (m != 0u) {
        const uint64_t* s = xz + (size_t)b * 8;   // broadcast loads
        const uint64_t x0 = s[0], x1 = s[1], x2 = s[2], x3 = s[3];
        const uint64_t z0 = s[4], z1 = s[5], z2 = s[6], z3 = s[7];
        const int base = IN_N - (__popcll(z0) + __popcll(z1) +
                                 __popcll(z2) + __popcll(z3));
        const uint64_t* wp = wbits + (size_t)m * (OUT_N * 4);
        #pragma unroll
        for (int q = 0; q < 4; ++q) {
            const int o = q * 64 + lane;
            const uint64_t* w4 = wp + (size_t)o * 4;
            const ulonglong2 a = *reinterpret_cast<const ulonglong2*>(w4);
            const ulonglong2 c = *reinterpret_cast<const ulonglong2*>(w4 + 2);
            const int d = __popcll((x0 ^ a.x) & ~z0)
                        + __popcll((x1 ^ a.y) & ~z1)
                        + __popcll((x2 ^ c.x) & ~z2)
                        + __popcll((x3 ^ c.y) & ~z3);
            ob[o] = (float)(base - 2 * d) * scale[o];
        }
    } else {
        #pragma unroll
        for (int q = 0; q < 4; ++q) ob[q * 64 + lane] = 0.0f;
    }
}

// ---------------------------------------------------------------------------
extern "C" void kernel_launch(void* const* d_in, const int* in_sizes, int n_in,
                              void* d_out, int out_size, void* d_ws, size_t ws_size,
                              hipStream_t stream) {
    const float* x     = (const float*)d_in[0];   // [B,1,IN]
    const float* W     = (const float*)d_in[1];   // [1,E,IN,OUT]
    const float* pw    = (const float*)d_in[2];   // [E,IN]
    const float* pb    = (const float*)d_in[3];   // [E]
    const float* scale = (const float*)d_in[4];   // [1,1,OUT]
    float*       out   = (float*)d_out;           // [B,1,OUT]

    uint64_t* wbits = (uint64_t*)d_ws;                 // 2 MiB
    uint64_t* xz    = (uint64_t*)d_ws + XZ_OFF_U64;    // 256 KiB
    uint32_t* masks = (uint32_t*)((uint64_t*)d_ws + XZ_OFF_U64 + (size_t)B_N * 8);

    hipLaunchKernelGGL(prep, dim3(256 + B_N / 4), dim3(256), 0, stream,
                       W, x, pw, pb, wbits, xz, masks);
    hipLaunchKernelGGL(popc_gemv, dim3(B_N / 4), dim3(256), 0, stream,
                       wbits, xz, masks, scale, out);
}